// Round 17
// baseline (178.904 us; speedup 1.0000x reference)
//
#include <hip/hip_runtime.h>
#include <hip/hip_bf16.h>
#include <cstdint>
#include <cstddef>

#define E_N 500000
#define FD 128
#define TD 100
#define OD 128
#define NT 4
#define IND 228   // FD + TD
#define KP 256    // K padded to MFMA multiple
#define GX 256    // chunks per type for gemm
#define NB 1954   // ceil(E_N/256) histogram blocks
#define EPS 136   // epilogue LDS row stride in floats

// workspace layout (bytes)
static constexpr size_t BUCKET_OFF = 0;                                   // int[E_N]
static constexpr size_t WBF_OFF    = 2000000;                             // bf16[NT][OD][KP]
static constexpr size_t BIASC_OFF  = WBF_OFF + (size_t)NT * OD * KP * 2;  // float[NT][OD]
static constexpr size_t CTR_OFF    = BIASC_OFF + (size_t)NT * OD * 4;     // int[16]
static constexpr size_t PART_OFF   = CTR_OFF + 64;                        // int[NB*4]
static constexpr size_t BBASE_OFF  = PART_OFF + (size_t)NB * 4 * 4;       // int[NB*4]
static constexpr size_t WS_NEED    = BBASE_OFF + (size_t)NB * 4 * 4;

typedef __attribute__((ext_vector_type(8))) short short8;
typedef __attribute__((ext_vector_type(4))) float f32x4;

__device__ __forceinline__ unsigned short f2bf(float x) {
  union { float f; unsigned u; } v; v.f = x;
  unsigned r = v.u + 0x7fff + ((v.u >> 16) & 1);   // RNE, inputs are finite
  return (unsigned short)(r >> 16);
}

// packed f32x2 -> bf16x2 via the HIP LIBRARY intrinsic (RNE; proper compiler
// semantics). NOT the hand-rolled v_cvt_pk_bf16_f32 asm -- that corrupted
// r3/r14 (absmax ~0.85) and is banned.
__device__ __forceinline__ unsigned pack2bf(float a, float b) {
  union { __hip_bfloat162 h; unsigned u; } c;
  c.h = __float22bfloat162_rn(make_float2(a, b));   // a -> low 16, b -> high 16
  return c.u;
}

// swizzled byte offset into the A tile: row r (0..63), k elem (0..255), bf16.
__device__ __forceinline__ int a_off(int r, int k) {
  return ((r << 9) + (k << 1)) ^ ((r & 7) << 4);
}

// epilogue LDS word offset: row (edge 0..63), slot (16B chunk 0..31 of the row)
__device__ __forceinline__ int ep_w(int row, int slot) {
  return row * EPS + ((slot ^ (row & 7)) << 2);
}

// per-block type histogram (1 edge/thread, ballot counts, no atomics)
__global__ void hist_kernel(const int* __restrict__ types, int* __restrict__ partial, int n) {
  __shared__ int wcnt[4][NT];
  const int tid = threadIdx.x, w = tid >> 6, l = tid & 63;
  const int i = blockIdx.x * 256 + tid;
  const int t = (i < n) ? types[i] : -1;
  #pragma unroll
  for (int q = 0; q < NT; ++q) {
    unsigned long long m = __ballot(t == q);
    if (l == 0) wcnt[w][q] = (int)__popcll(m);
  }
  __syncthreads();
  if (tid < NT) {
    int s = 0;
    #pragma unroll
    for (int w2 = 0; w2 < 4; ++w2) s += wcnt[w2][tid];
    partial[blockIdx.x * NT + tid] = s;
  }
}

// single block: exclusive scan of per-block counts -> blockbase; type totals ->
// ctr[0..3]=counts, ctr[4..7]=offsets. Fused bias precompute. Deterministic.
__global__ void scan_kernel(const int* __restrict__ partial, int* __restrict__ blockbase,
                            int* __restrict__ ctr, const float* __restrict__ b,
                            const float* __restrict__ temb, float* __restrict__ biasc) {
  __shared__ int4 tsum[256];
  const int tid = threadIdx.x;
  int4 s = make_int4(0, 0, 0, 0);
  #pragma unroll
  for (int j = 0; j < 8; ++j) {
    int blk = tid * 8 + j;
    if (blk < NB) {
      const int* p = partial + blk * 4;
      s.x += p[0]; s.y += p[1]; s.z += p[2]; s.w += p[3];
    }
  }
  tsum[tid] = s;
  __syncthreads();
  if (tid == 0) {
    int4 run = make_int4(0, 0, 0, 0);
    for (int i = 0; i < 256; ++i) {
      int4 v = tsum[i]; tsum[i] = run;
      run.x += v.x; run.y += v.y; run.z += v.z; run.w += v.w;
    }
    ctr[0] = run.x; ctr[1] = run.y; ctr[2] = run.z; ctr[3] = run.w;
    int off = 0;
    ctr[4] = 0;            off += run.x;
    ctr[5] = off;          off += run.y;
    ctr[6] = off;          off += run.z;
    ctr[7] = off;
  }
  __syncthreads();
  int4 run = tsum[tid];
  #pragma unroll
  for (int j = 0; j < 8; ++j) {
    int blk = tid * 8 + j;
    if (blk < NB) {
      const int* p = partial + blk * 4;
      int* bb = blockbase + blk * 4;
      bb[0] = run.x; bb[1] = run.y; bb[2] = run.z; bb[3] = run.w;
      run.x += p[0]; run.y += p[1]; run.z += p[2]; run.w += p[3];
    }
  }
  for (int i = tid; i < NT * OD; i += 256) biasc[i] = b[i] + temb[i];
}

// W [NT][IND][OD] f32 -> Wbf [NT][OD][KP] bf16 (N-major, K zero-padded beyond 228)
__global__ void wconv_kernel(const float* __restrict__ W, unsigned short* __restrict__ Wbf) {
  int row = blockIdx.x * 4 + (threadIdx.x >> 6);   // row = t*OD + n, 0..511
  int t = row >> 7, n = row & 127;
  int k0 = (threadIdx.x & 63) << 2;
  ushort4 o;
  float v0 = (k0 + 0 < IND) ? W[((size_t)t * IND + k0 + 0) * OD + n] : 0.f;
  float v1 = (k0 + 1 < IND) ? W[((size_t)t * IND + k0 + 1) * OD + n] : 0.f;
  float v2 = (k0 + 2 < IND) ? W[((size_t)t * IND + k0 + 2) * OD + n] : 0.f;
  float v3 = (k0 + 3 < IND) ? W[((size_t)t * IND + k0 + 3) * OD + n] : 0.f;
  o.x = f2bf(v0); o.y = f2bf(v1); o.z = f2bf(v2); o.w = f2bf(v3);
  *(ushort4*)(Wbf + ((size_t)row << 8) + k0) = o;
}

// deterministic SORTED fill: pos = type_off + blockbase[b][t] + in-block rank.
__global__ void fill_kernel(const int* __restrict__ types, const int* __restrict__ blockbase,
                            const int* __restrict__ ctr, int* __restrict__ bucket, int n) {
  __shared__ int wcnt[4][NT];
  __shared__ int wbase[4][NT];
  const int tid = threadIdx.x, w = tid >> 6, l = tid & 63;
  const int i = blockIdx.x * 256 + tid;
  const int t = (i < n) ? types[i] : -1;
  unsigned long long m[NT];
  #pragma unroll
  for (int q = 0; q < NT; ++q) {
    m[q] = __ballot(t == q);
    if (l == 0) wcnt[w][q] = (int)__popcll(m[q]);
  }
  __syncthreads();
  if (tid < NT) {
    int q = tid, s = 0;
    #pragma unroll
    for (int w2 = 0; w2 < 4; ++w2) { wbase[w2][q] = s; s += wcnt[w2][q]; }
  }
  __syncthreads();
  if (t >= 0) {
    int rank = wbase[w][t] + (int)__popcll(m[t] & ((1ull << l) - 1ull));
    bucket[ctr[4 + t] + blockbase[blockIdx.x * 4 + t] + rank] = i;
  }
}

// Main kernel: r16 structure (proven), stage packing via __float22bfloat162_rn
// (1 packed convert per 2 elems vs ~7 scalar ops -> stage VALU ~halved).
__global__ __launch_bounds__(256) void gemm_kernel(
    const float* __restrict__ feats, const float* __restrict__ ts,
    const float* __restrict__ freqs, const unsigned short* __restrict__ Wbf,
    const float* __restrict__ biasc, const int* __restrict__ bucket,
    const int* __restrict__ ctr, float* __restrict__ out) {
  __shared__ __align__(16) char smraw[64 * EPS * 4];
  __shared__ __align__(16) float sfreq[128];

  const int t = blockIdx.x;
  const int cnt = ctr[t];
  const int off = ctr[4 + t];
  const int ntiles = (cnt + 63) >> 6;
  const int chunk = (ntiles + GX - 1) / GX;
  const int t0 = blockIdx.y * chunk;
  const int t1 = min(t0 + chunk, ntiles);
  if (t0 >= t1) return;

  const int tid = threadIdx.x;
  const int wid = tid >> 6, lane = tid & 63;
  const int bl = lane & 15, bh = lane >> 4;
  const int r = tid >> 2, part = tid & 3;   // 4 threads per A-row; part = 32-elem window

  // W fragments, first MFMA operand (A-layout): lane bl <-> out-col, k-window bh*8
  short8 bfrag[8][2];
  #pragma unroll
  for (int n = 0; n < 2; ++n) {
    const unsigned short* bp =
        Wbf + (((size_t)t * OD + wid * 32 + n * 16 + bl) << 8) + (bh << 3);
    #pragma unroll
    for (int k = 0; k < 8; ++k) bfrag[k][n] = *(const short8*)(bp + k * 32);
  }
  // bias for this lane's cols: col = wid*32 + n*16 + bh*4 + j
  const float4 bv0 = *(const float4*)(biasc + t * OD + wid * 32 + bh * 4);
  const float4 bv1 = *(const float4*)(biasc + t * OD + wid * 32 + 16 + bh * 4);

  if (tid < 128) sfreq[tid] = (tid < TD) ? freqs[t * TD + tid] : 0.f;

  auto stage = [&](const float4* p, float tvv) {
    #pragma unroll
    for (int j = 0; j < 4; ++j) {
      uint4 q;
      q.x = pack2bf(p[2 * j].x, p[2 * j].y);
      q.y = pack2bf(p[2 * j].z, p[2 * j].w);
      q.z = pack2bf(p[2 * j + 1].x, p[2 * j + 1].y);
      q.w = pack2bf(p[2 * j + 1].z, p[2 * j + 1].w);
      *(uint4*)(smraw + a_off(r, part * 32 + 8 * j)) = q;
    }
    #pragma unroll
    for (int j = 0; j < 4; ++j) {
      float4 f0 = *(const float4*)&sfreq[part * 32 + 8 * j];
      float4 f1 = *(const float4*)&sfreq[part * 32 + 8 * j + 4];
      uint4 q;
      q.x = pack2bf(__cosf(tvv * f0.x), __cosf(tvv * f0.y));
      q.y = pack2bf(__cosf(tvv * f0.z), __cosf(tvv * f0.w));
      q.z = pack2bf(__cosf(tvv * f1.x), __cosf(tvv * f1.y));
      q.w = pack2bf(__cosf(tvv * f1.z), __cosf(tvv * f1.w));
      *(uint4*)(smraw + a_off(r, FD + part * 32 + 8 * j)) = q;
    }
  };

  // ---- prologue ----
  int e_cur = -1; float tv_cur = 0.f;
  {
    const int va = min(64, cnt - t0 * 64);
    if (r < va) { e_cur = bucket[off + t0 * 64 + r]; tv_cur = ts[e_cur]; }
  }
  float4 pf[8];
  if (e_cur >= 0) {
    const float4* src = (const float4*)(feats + (size_t)e_cur * FD + part * 32);
    #pragma unroll
    for (int c = 0; c < 8; ++c) pf[c] = src[c];
  }
  int e_b = -1; float tv_b = 0.f;
  if (t0 + 1 < t1) {
    const int vb = min(64, cnt - (t0 + 1) * 64);
    if (r < vb) { e_b = bucket[off + (t0 + 1) * 64 + r]; tv_b = ts[e_b]; }
  }
  __syncthreads();                    // sfreq visible
  if (e_cur >= 0) stage(pf, tv_cur);

  for (int tt = t0; tt < t1; ++tt) {
    const bool last = (tt == t1 - 1);
    __syncthreads();   // A(tt) ready

    if (!last && e_b >= 0) {
      const float4* src = (const float4*)(feats + (size_t)e_b * FD + part * 32);
      #pragma unroll
      for (int c = 0; c < 8; ++c) pf[c] = src[c];
    }
    int e_c = -1; float tv_c = 0.f;
    if (tt + 2 < t1) {
      const int vc = min(64, cnt - (tt + 2) * 64);
      if (r < vc) { e_c = bucket[off + (tt + 2) * 64 + r]; tv_c = ts[e_c]; }
    }

    // ---- MFMA, bias in acc-init ----
    f32x4 acc[4][2];
    #pragma unroll
    for (int rt = 0; rt < 4; ++rt) {
      acc[rt][0][0] = bv0.x; acc[rt][0][1] = bv0.y; acc[rt][0][2] = bv0.z; acc[rt][0][3] = bv0.w;
      acc[rt][1][0] = bv1.x; acc[rt][1][1] = bv1.y; acc[rt][1][2] = bv1.z; acc[rt][1][3] = bv1.w;
    }
    __builtin_amdgcn_s_setprio(1);
    #pragma unroll
    for (int rt = 0; rt < 4; ++rt) {
      #pragma unroll
      for (int k = 0; k < 8; ++k) {
        short8 av = *(const short8*)(smraw + a_off(rt * 16 + bl, k * 32 + bh * 8));
        acc[rt][0] = __builtin_amdgcn_mfma_f32_16x16x32_bf16(bfrag[k][0], av, acc[rt][0], 0, 0, 0);
        acc[rt][1] = __builtin_amdgcn_mfma_f32_16x16x32_bf16(bfrag[k][1], av, acc[rt][1], 0, 0, 0);
      }
    }
    __builtin_amdgcn_s_setprio(0);
    __syncthreads();   // A reads done; region reusable

    // ---- epilogue write: lane -> row rt*16+bl, slot wid*8+{0,4}+bh ----
    float* ep = (float*)smraw;
    #pragma unroll
    for (int rt = 0; rt < 4; ++rt) {
      *(f32x4*)(ep + ep_w(rt * 16 + bl, wid * 8 + 0 + bh)) = acc[rt][0];
      *(f32x4*)(ep + ep_w(rt * 16 + bl, wid * 8 + 4 + bh)) = acc[rt][1];
    }
    __syncthreads();   // epilogue visible

    // ---- store: thread owns its row's cols part*32..+31 (full-line pattern) ----
    if (e_cur >= 0) {
      float* dst = out + (size_t)e_cur * OD + part * 32;
      #pragma unroll
      for (int c = 0; c < 8; ++c) {
        f32x4 v = *(const f32x4*)(ep + ep_w(r, part * 8 + c));
        *(f32x4*)(dst + 4 * c) = v;
      }
    }

    if (!last) {
      __syncthreads();   // ep reads done before next stage overwrites
      if (e_b >= 0) stage(pf, tv_b);
      e_cur = e_b; tv_cur = tv_b;
      e_b = e_c; tv_b = tv_c;
    }
  }
}

// correctness fallback if ws is too small (fp32 vector path)
__global__ void naive_kernel(const float* __restrict__ feats, const float* __restrict__ ts,
                             const int* __restrict__ types, const float* __restrict__ W,
                             const float* __restrict__ b, const float* __restrict__ temb,
                             const float* __restrict__ freqs, float* __restrict__ out) {
  __shared__ float comb[IND];
  int e = blockIdx.x;
  int t = types[e];
  int tid = threadIdx.x;  // 128 threads
  comb[tid] = feats[(size_t)e * FD + tid];
  if (tid < TD) comb[FD + tid] = __cosf(ts[e] * freqs[t * TD + tid]);
  __syncthreads();
  float acc = b[t * OD + tid] + temb[t * OD + tid];
  for (int k = 0; k < IND; ++k) acc += comb[k] * W[((size_t)t * IND + k) * OD + tid];
  out[(size_t)e * OD + tid] = acc;
}

extern "C" void kernel_launch(void* const* d_in, const int* in_sizes, int n_in,
                              void* d_out, int out_size, void* d_ws, size_t ws_size,
                              hipStream_t stream) {
  const float* feats = (const float*)d_in[0];
  const float* ts    = (const float*)d_in[1];
  const int*   types = (const int*)d_in[2];
  const float* W     = (const float*)d_in[3];
  const float* bb    = (const float*)d_in[4];
  const float* temb  = (const float*)d_in[5];
  const float* freqs = (const float*)d_in[6];
  float* out = (float*)d_out;

  if (ws_size < WS_NEED) {
    naive_kernel<<<E_N, 128, 0, stream>>>(feats, ts, types, W, bb, temb, freqs, out);
    return;
  }

  char* ws = (char*)d_ws;
  int* bucket = (int*)(ws + BUCKET_OFF);
  unsigned short* Wbf = (unsigned short*)(ws + WBF_OFF);
  float* biasc = (float*)(ws + BIASC_OFF);
  int* ctr = (int*)(ws + CTR_OFF);
  int* partial = (int*)(ws + PART_OFF);
  int* blockbase = (int*)(ws + BBASE_OFF);

  hist_kernel<<<NB, 256, 0, stream>>>(types, partial, E_N);
  scan_kernel<<<1, 256, 0, stream>>>(partial, blockbase, ctr, bb, temb, biasc);
  wconv_kernel<<<(NT * OD) / 4, 256, 0, stream>>>(W, Wbf);
  fill_kernel<<<NB, 256, 0, stream>>>(types, blockbase, ctr, bucket, E_N);
  dim3 g(NT, GX);
  gemm_kernel<<<g, 256, 0, stream>>>(feats, ts, freqs, Wbf, biasc, bucket, ctr, out);
}

// Round 18
// 152.653 us; speedup vs baseline: 1.1720x; 1.1720x over previous
//
#include <hip/hip_runtime.h>
#include <hip/hip_bf16.h>
#include <cstdint>
#include <cstddef>

#define E_N 500000
#define FD 128
#define TD 100
#define OD 128
#define NT 4
#define IND 228   // FD + TD
#define KP 256    // K padded to MFMA multiple
#define GX 256    // chunks per type for gemm
#define NB 1954   // ceil(E_N/256) histogram blocks

// workspace layout (bytes)
static constexpr size_t BUCKET_OFF = 0;                                   // int[E_N]
static constexpr size_t WBF_OFF    = 2000000;                             // bf16[NT][OD][KP]
static constexpr size_t BIASC_OFF  = WBF_OFF + (size_t)NT * OD * KP * 2;  // float[NT][OD]
static constexpr size_t CTR_OFF    = BIASC_OFF + (size_t)NT * OD * 4;     // int[16]
static constexpr size_t PART_OFF   = CTR_OFF + 64;                        // int[NB*4]
static constexpr size_t BBASE_OFF  = PART_OFF + (size_t)NB * 4 * 4;       // int[NB*4]
static constexpr size_t WS_NEED    = BBASE_OFF + (size_t)NB * 4 * 4;

typedef __attribute__((ext_vector_type(8))) short short8;
typedef __attribute__((ext_vector_type(4))) float f32x4;

__device__ __forceinline__ unsigned short f2bf(float x) {
  union { float f; unsigned u; } v; v.f = x;
  unsigned r = v.u + 0x7fff + ((v.u >> 16) & 1);   // RNE, inputs are finite
  return (unsigned short)(r >> 16);
}

// packed f32x2 -> bf16x2 via the HIP library intrinsic (RNE). The hand-rolled
// v_cvt_pk_bf16_f32 inline asm corrupted r3/r14 (absmax ~0.85) -- banned.
__device__ __forceinline__ unsigned pack2bf(float a, float b) {
  union { __hip_bfloat162 h; unsigned u; } c;
  c.h = __float22bfloat162_rn(make_float2(a, b));
  return c.u;
}

// swizzled byte offset into the A tile: row r (0..63), k elem (0..255), bf16.
__device__ __forceinline__ int a_off(int r, int k) {
  return ((r << 9) + (k << 1)) ^ ((r & 7) << 4);
}

// per-block type histogram (1 edge/thread, ballot counts, no atomics)
__global__ void hist_kernel(const int* __restrict__ types, int* __restrict__ partial, int n) {
  __shared__ int wcnt[4][NT];
  const int tid = threadIdx.x, w = tid >> 6, l = tid & 63;
  const int i = blockIdx.x * 256 + tid;
  const int t = (i < n) ? types[i] : -1;
  #pragma unroll
  for (int q = 0; q < NT; ++q) {
    unsigned long long m = __ballot(t == q);
    if (l == 0) wcnt[w][q] = (int)__popcll(m);
  }
  __syncthreads();
  if (tid < NT) {
    int s = 0;
    #pragma unroll
    for (int w2 = 0; w2 < 4; ++w2) s += wcnt[w2][tid];
    partial[blockIdx.x * NT + tid] = s;
  }
}

// single block: exclusive scan of per-block counts -> blockbase; type totals ->
// ctr[0..3]=counts, ctr[4..7]=offsets. Fused bias precompute. Deterministic.
__global__ void scan_kernel(const int* __restrict__ partial, int* __restrict__ blockbase,
                            int* __restrict__ ctr, const float* __restrict__ b,
                            const float* __restrict__ temb, float* __restrict__ biasc) {
  __shared__ int4 tsum[256];
  const int tid = threadIdx.x;
  int4 s = make_int4(0, 0, 0, 0);
  #pragma unroll
  for (int j = 0; j < 8; ++j) {
    int blk = tid * 8 + j;
    if (blk < NB) {
      const int* p = partial + blk * 4;
      s.x += p[0]; s.y += p[1]; s.z += p[2]; s.w += p[3];
    }
  }
  tsum[tid] = s;
  __syncthreads();
  if (tid == 0) {
    int4 run = make_int4(0, 0, 0, 0);
    for (int i = 0; i < 256; ++i) {
      int4 v = tsum[i]; tsum[i] = run;
      run.x += v.x; run.y += v.y; run.z += v.z; run.w += v.w;
    }
    ctr[0] = run.x; ctr[1] = run.y; ctr[2] = run.z; ctr[3] = run.w;
    int off = 0;
    ctr[4] = 0;            off += run.x;
    ctr[5] = off;          off += run.y;
    ctr[6] = off;          off += run.z;
    ctr[7] = off;
  }
  __syncthreads();
  int4 run = tsum[tid];
  #pragma unroll
  for (int j = 0; j < 8; ++j) {
    int blk = tid * 8 + j;
    if (blk < NB) {
      const int* p = partial + blk * 4;
      int* bb = blockbase + blk * 4;
      bb[0] = run.x; bb[1] = run.y; bb[2] = run.z; bb[3] = run.w;
      run.x += p[0]; run.y += p[1]; run.z += p[2]; run.w += p[3];
    }
  }
  for (int i = tid; i < NT * OD; i += 256) biasc[i] = b[i] + temb[i];
}

// W [NT][IND][OD] f32 -> Wbf [NT][OD][KP] bf16 (N-major, K zero-padded beyond 228)
__global__ void wconv_kernel(const float* __restrict__ W, unsigned short* __restrict__ Wbf) {
  int row = blockIdx.x * 4 + (threadIdx.x >> 6);   // row = t*OD + n, 0..511
  int t = row >> 7, n = row & 127;
  int k0 = (threadIdx.x & 63) << 2;
  ushort4 o;
  float v0 = (k0 + 0 < IND) ? W[((size_t)t * IND + k0 + 0) * OD + n] : 0.f;
  float v1 = (k0 + 1 < IND) ? W[((size_t)t * IND + k0 + 1) * OD + n] : 0.f;
  float v2 = (k0 + 2 < IND) ? W[((size_t)t * IND + k0 + 2) * OD + n] : 0.f;
  float v3 = (k0 + 3 < IND) ? W[((size_t)t * IND + k0 + 3) * OD + n] : 0.f;
  o.x = f2bf(v0); o.y = f2bf(v1); o.z = f2bf(v2); o.w = f2bf(v3);
  *(ushort4*)(Wbf + ((size_t)row << 8) + k0) = o;
}

// deterministic SORTED fill: pos = type_off + blockbase[b][t] + in-block rank.
__global__ void fill_kernel(const int* __restrict__ types, const int* __restrict__ blockbase,
                            const int* __restrict__ ctr, int* __restrict__ bucket, int n) {
  __shared__ int wcnt[4][NT];
  __shared__ int wbase[4][NT];
  const int tid = threadIdx.x, w = tid >> 6, l = tid & 63;
  const int i = blockIdx.x * 256 + tid;
  const int t = (i < n) ? types[i] : -1;
  unsigned long long m[NT];
  #pragma unroll
  for (int q = 0; q < NT; ++q) {
    m[q] = __ballot(t == q);
    if (l == 0) wcnt[w][q] = (int)__popcll(m[q]);
  }
  __syncthreads();
  if (tid < NT) {
    int q = tid, s = 0;
    #pragma unroll
    for (int w2 = 0; w2 < 4; ++w2) { wbase[w2][q] = s; s += wcnt[w2][q]; }
  }
  __syncthreads();
  if (t >= 0) {
    int rank = wbase[w][t] + (int)__popcll(m[t] & ((1ull << l) - 1ull));
    bucket[ctr[4 + t] + blockbase[blockIdx.x * 4 + t] + rank] = i;
  }
}

// Main kernel: r17 minus the LDS epilogue. Swapped MFMA puts lane (bl,bh)'s
// acc at out[edge rt*16+bl][wid*32 + bh*4 (+16)] -> store DIRECTLY per
// row-subtile (acc = 8 live regs). 2 barriers/tile (was 4), zero epilogue LDS
// ops. The old direct-store condemnation (r5, WRITE=306MB) was confounded by
// launch_bounds(256,3) VGPR spills; this is the clean test.
__global__ __launch_bounds__(256) void gemm_kernel(
    const float* __restrict__ feats, const float* __restrict__ ts,
    const float* __restrict__ freqs, const unsigned short* __restrict__ Wbf,
    const float* __restrict__ biasc, const int* __restrict__ bucket,
    const int* __restrict__ ctr, float* __restrict__ out) {
  __shared__ __align__(16) char smA[64 * 512];      // A bf16 [64][256], XOR-swizzled
  __shared__ __align__(16) float sfreq[128];

  const int t = blockIdx.x;
  const int cnt = ctr[t];
  const int off = ctr[4 + t];
  const int ntiles = (cnt + 63) >> 6;
  const int chunk = (ntiles + GX - 1) / GX;
  const int t0 = blockIdx.y * chunk;
  const int t1 = min(t0 + chunk, ntiles);
  if (t0 >= t1) return;

  const int tid = threadIdx.x;
  const int wid = tid >> 6, lane = tid & 63;
  const int bl = lane & 15, bh = lane >> 4;
  const int r = tid >> 2, part = tid & 3;   // 4 threads per A-row; part = 32-elem window

  // W fragments, first MFMA operand (A-layout): lane bl <-> out-col, k-window bh*8
  short8 bfrag[8][2];
  #pragma unroll
  for (int n = 0; n < 2; ++n) {
    const unsigned short* bp =
        Wbf + (((size_t)t * OD + wid * 32 + n * 16 + bl) << 8) + (bh << 3);
    #pragma unroll
    for (int k = 0; k < 8; ++k) bfrag[k][n] = *(const short8*)(bp + k * 32);
  }
  // bias for this lane's cols: col = wid*32 + n*16 + bh*4 + j
  const float4 bv0 = *(const float4*)(biasc + t * OD + wid * 32 + bh * 4);
  const float4 bv1 = *(const float4*)(biasc + t * OD + wid * 32 + 16 + bh * 4);

  if (tid < 128) sfreq[tid] = (tid < TD) ? freqs[t * TD + tid] : 0.f;

  auto stage = [&](const float4* p, float tvv) {
    #pragma unroll
    for (int j = 0; j < 4; ++j) {
      uint4 q;
      q.x = pack2bf(p[2 * j].x, p[2 * j].y);
      q.y = pack2bf(p[2 * j].z, p[2 * j].w);
      q.z = pack2bf(p[2 * j + 1].x, p[2 * j + 1].y);
      q.w = pack2bf(p[2 * j + 1].z, p[2 * j + 1].w);
      *(uint4*)(smA + a_off(r, part * 32 + 8 * j)) = q;
    }
    #pragma unroll
    for (int j = 0; j < 4; ++j) {
      float4 f0 = *(const float4*)&sfreq[part * 32 + 8 * j];
      float4 f1 = *(const float4*)&sfreq[part * 32 + 8 * j + 4];
      uint4 q;
      q.x = pack2bf(__cosf(tvv * f0.x), __cosf(tvv * f0.y));
      q.y = pack2bf(__cosf(tvv * f0.z), __cosf(tvv * f0.w));
      q.z = pack2bf(__cosf(tvv * f1.x), __cosf(tvv * f1.y));
      q.w = pack2bf(__cosf(tvv * f1.z), __cosf(tvv * f1.w));
      *(uint4*)(smA + a_off(r, FD + part * 32 + 8 * j)) = q;
    }
  };

  // ---- prologue ----
  int e_cur = -1; float tv_cur = 0.f;
  {
    const int va = min(64, cnt - t0 * 64);
    if (r < va) { e_cur = bucket[off + t0 * 64 + r]; tv_cur = ts[e_cur]; }
  }
  float4 pf[8];
  if (e_cur >= 0) {
    const float4* src = (const float4*)(feats + (size_t)e_cur * FD + part * 32);
    #pragma unroll
    for (int c = 0; c < 8; ++c) pf[c] = src[c];
  }
  int e_b = -1; float tv_b = 0.f;
  if (t0 + 1 < t1) {
    const int vb = min(64, cnt - (t0 + 1) * 64);
    if (r < vb) { e_b = bucket[off + (t0 + 1) * 64 + r]; tv_b = ts[e_b]; }
  }
  __syncthreads();                    // sfreq visible
  if (e_cur >= 0) stage(pf, tv_cur);

  for (int tt = t0; tt < t1; ++tt) {
    const bool last = (tt == t1 - 1);
    __syncthreads();   // A(tt) ready

    // prefetch feats(tt+1) -> regs (rides under MFMA; drains at next barrier)
    if (!last && e_b >= 0) {
      const float4* src = (const float4*)(feats + (size_t)e_b * FD + part * 32);
      #pragma unroll
      for (int c = 0; c < 8; ++c) pf[c] = src[c];
    }
    // issue idx(tt+2): bucket->ts chain covered by a full iteration
    int e_c = -1; float tv_c = 0.f;
    if (tt + 2 < t1) {
      const int vc = min(64, cnt - (tt + 2) * 64);
      if (r < vc) { e_c = bucket[off + (tt + 2) * 64 + r]; tv_c = ts[e_c]; }
    }
    // edge indices of the 4 row-subtiles this lane stores (sorted bucket, L1-hot)
    const int base = tt * 64;
    const int vcnt = cnt - base;   // >0
    int se[4];
    #pragma unroll
    for (int rt = 0; rt < 4; ++rt) {
      int rr = rt * 16 + bl;
      se[rt] = (rr < vcnt) ? bucket[off + base + rr] : -1;
    }

    // ---- MFMA per row-subtile, bias in acc-init, DIRECT store ----
    __builtin_amdgcn_s_setprio(1);
    #pragma unroll
    for (int rt = 0; rt < 4; ++rt) {
      f32x4 a0, a1;
      a0[0] = bv0.x; a0[1] = bv0.y; a0[2] = bv0.z; a0[3] = bv0.w;
      a1[0] = bv1.x; a1[1] = bv1.y; a1[2] = bv1.z; a1[3] = bv1.w;
      #pragma unroll
      for (int k = 0; k < 8; ++k) {
        short8 av = *(const short8*)(smA + a_off(rt * 16 + bl, k * 32 + bh * 8));
        a0 = __builtin_amdgcn_mfma_f32_16x16x32_bf16(bfrag[k][0], av, a0, 0, 0, 0);
        a1 = __builtin_amdgcn_mfma_f32_16x16x32_bf16(bfrag[k][1], av, a1, 0, 0, 0);
      }
      if (se[rt] >= 0) {
        float* dst = out + (size_t)se[rt] * OD + wid * 32 + bh * 4;
        *(f32x4*)(dst)      = a0;
        *(f32x4*)(dst + 16) = a1;
      }
    }
    __builtin_amdgcn_s_setprio(0);
    __syncthreads();   // A reads done; prefetch+stores drained; region reusable

    if (!last) {
      if (e_b >= 0) stage(pf, tv_b);
      e_cur = e_b; tv_cur = tv_b;
      e_b = e_c; tv_b = tv_c;
    }
  }
}

// correctness fallback if ws is too small (fp32 vector path)
__global__ void naive_kernel(const float* __restrict__ feats, const float* __restrict__ ts,
                             const int* __restrict__ types, const float* __restrict__ W,
                             const float* __restrict__ b, const float* __restrict__ temb,
                             const float* __restrict__ freqs, float* __restrict__ out) {
  __shared__ float comb[IND];
  int e = blockIdx.x;
  int t = types[e];
  int tid = threadIdx.x;  // 128 threads
  comb[tid] = feats[(size_t)e * FD + tid];
  if (tid < TD) comb[FD + tid] = __cosf(ts[e] * freqs[t * TD + tid]);
  __syncthreads();
  float acc = b[t * OD + tid] + temb[t * OD + tid];
  for (int k = 0; k < IND; ++k) acc += comb[k] * W[((size_t)t * IND + k) * OD + tid];
  out[(size_t)e * OD + tid] = acc;
}

extern "C" void kernel_launch(void* const* d_in, const int* in_sizes, int n_in,
                              void* d_out, int out_size, void* d_ws, size_t ws_size,
                              hipStream_t stream) {
  const float* feats = (const float*)d_in[0];
  const float* ts    = (const float*)d_in[1];
  const int*   types = (const int*)d_in[2];
  const float* W     = (const float*)d_in[3];
  const float* bb    = (const float*)d_in[4];
  const float* temb  = (const float*)d_in[5];
  const float* freqs = (const float*)d_in[6];
  float* out = (float*)d_out;

  if (ws_size < WS_NEED) {
    naive_kernel<<<E_N, 128, 0, stream>>>(feats, ts, types, W, bb, temb, freqs, out);
    return;
  }

  char* ws = (char*)d_ws;
  int* bucket = (int*)(ws + BUCKET_OFF);
  unsigned short* Wbf = (unsigned short*)(ws + WBF_OFF);
  float* biasc = (float*)(ws + BIASC_OFF);
  int* ctr = (int*)(ws + CTR_OFF);
  int* partial = (int*)(ws + PART_OFF);
  int* blockbase = (int*)(ws + BBASE_OFF);

  hist_kernel<<<NB, 256, 0, stream>>>(types, partial, E_N);
  scan_kernel<<<1, 256, 0, stream>>>(partial, blockbase, ctr, bb, temb, biasc);
  wconv_kernel<<<(NT * OD) / 4, 256, 0, stream>>>(W, Wbf);
  fill_kernel<<<NB, 256, 0, stream>>>(types, blockbase, ctr, bucket, E_N);
  dim3 g(NT, GX);
  gemm_kernel<<<g, 256, 0, stream>>>(feats, ts, freqs, Wbf, biasc, bucket, ctr, out);
}